// Round 6
// baseline (615.970 us; speedup 1.0000x reference)
//
#include <hip/hip_runtime.h>
#include <hip/hip_bf16.h>
#include <stdint.h>

typedef __attribute__((ext_vector_type(8))) short short8;
typedef __attribute__((ext_vector_type(4))) float f32x4;
typedef unsigned int u32;
typedef unsigned short u16;

static constexpr int N_TOK = 1024;
static constexpr int DDIM = 2048;
static constexpr int FDIM = 1408;
static constexpr int NEXP = 8;
static constexpr int MAXROWS = 3072;    // 2048 + 8*127 < 3072 (128-row padding)
static constexpr int NT128 = 24;        // max 128-row tiles

// ---- workspace byte offsets ----
static constexpr size_t O_META   = 0;                                  // 64 ints
static constexpr size_t O_TE128  = 256;                                // 24 ints
static constexpr size_t O_TR128  = 384;                                // 24 ints
static constexpr size_t O_ROWTOK = 768;                                // MAXROWS ints
static constexpr size_t O_TOKROWS= O_ROWTOK + (size_t)MAXROWS * 4;     // 2048 ints
static constexpr size_t O_SEL    = O_TOKROWS + 2048 * 4;               // 2048 ints
static constexpr size_t O_W      = O_SEL + 2048 * 4;                   // 2048 floats
static constexpr size_t O_H      = (O_W + 2048 * 4 + 255) & ~(size_t)255; // MAXROWS*FDIM bf16
static constexpr size_t O_EO     = O_H + (size_t)MAXROWS * FDIM * 2;   // MAXROWS*DDIM bf16

static __device__ __forceinline__ u16 f2bf(float f) {
    return __builtin_bit_cast(u16, __float2bfloat16(f));   // RNE via v_cvt
}
static __device__ __forceinline__ float bf2f(u16 s) {
    u32 u = ((u32)s) << 16;
    return __builtin_bit_cast(float, u);
}
static __device__ __forceinline__ u32 pack2(float a, float b) {
    return (u32)f2bf(a) | ((u32)f2bf(b) << 16);
}

// ---------------- router: logits, top-2, softmax ----------------
__global__ __launch_bounds__(256) void router_kernel(
    const float* __restrict__ x, const float* __restrict__ gw,
    int* __restrict__ sel, float* __restrict__ wout)
{
    __shared__ float xs[DDIM];
    __shared__ float lg[NEXP];
    const int tok = blockIdx.x;
    const float* xr = x + (size_t)tok * DDIM;
    for (int i = threadIdx.x; i < DDIM / 4; i += 256)
        ((float4*)xs)[i] = ((const float4*)xr)[i];
    __syncthreads();
    const int wid = threadIdx.x >> 6, lane = threadIdx.x & 63;
    for (int i = 0; i < 2; i++) {
        const int e = wid * 2 + i;
        const float* g = gw + (size_t)e * DDIM;
        float s = 0.f;
        for (int k = lane; k < DDIM; k += 64) s += xs[k] * g[k];
        for (int off = 32; off > 0; off >>= 1) s += __shfl_down(s, off);
        if (lane == 0) lg[e] = s;
    }
    __syncthreads();
    if (threadIdx.x == 0) {
        int i1 = 0;
        for (int e = 1; e < NEXP; e++) if (lg[e] > lg[i1]) i1 = e;
        int i2 = -1;
        for (int e = 0; e < NEXP; e++) {
            if (e == i1) continue;
            if (i2 < 0 || lg[e] > lg[i2]) i2 = e;
        }
        const float e2 = __expf(lg[i2] - lg[i1]);
        const float w1 = 1.f / (1.f + e2);
        sel[tok * 2] = i1; sel[tok * 2 + 1] = i2;
        wout[tok * 2] = w1; wout[tok * 2 + 1] = e2 * w1;
    }
}

// -------- deterministic routing build (1 block, 8 waves); 128-row padding ----
__global__ __launch_bounds__(512) void build_kernel(
    const int* __restrict__ sel,
    int* __restrict__ meta, int* __restrict__ te128, int* __restrict__ tr128,
    int* __restrict__ row_tok, int* __restrict__ tok_rows)
{
    __shared__ int s0[N_TOK], s1[N_TOK];
    __shared__ u16 p0[N_TOK], p1[N_TOK];
    __shared__ int counts[NEXP], offs[NEXP];
    for (int i = threadIdx.x; i < N_TOK; i += 512) {
        s0[i] = sel[i * 2]; s1[i] = sel[i * 2 + 1];
    }
    __syncthreads();
    const int e = threadIdx.x >> 6, lane = threadIdx.x & 63;
    int base = 0;
    for (int c = 0; c < N_TOK / 64; c++) {
        const int tk = c * 64 + lane;
        const int slot = (s0[tk] == e) ? 0 : ((s1[tk] == e) ? 1 : -1);
        const unsigned long long m = __ballot(slot >= 0);
        const int pre = __popcll(m & ((1ull << lane) - 1ull));
        if (slot == 0) p0[tk] = (u16)(base + pre);
        else if (slot == 1) p1[tk] = (u16)(base + pre);
        base += __popcll(m);
    }
    if (lane == 0) counts[e] = base;
    __syncthreads();
    if (threadIdx.x == 0) {
        int off = 0, n128 = 0;
        for (int qq = 0; qq < NEXP; qq++) {
            offs[qq] = off;
            const int pc = (counts[qq] + 127) & ~127;
            for (int i = 0; i < pc / 128; i++) { te128[n128] = qq; tr128[n128] = off + i * 128; n128++; }
            off += pc;
        }
        meta[0] = n128; meta[1] = off;
    }
    __syncthreads();
    const int off = offs[e];
    for (int c = 0; c < N_TOK / 64; c++) {
        const int tk = c * 64 + lane;
        const int slot = (s0[tk] == e) ? 0 : ((s1[tk] == e) ? 1 : -1);
        if (slot >= 0) {
            const int row = off + (slot ? p1[tk] : p0[tk]);
            row_tok[row] = tk;
            tok_rows[tk * 2 + slot] = row;
        }
    }
    const int cnt = counts[e];
    const int pc = (cnt + 127) & ~127;
    for (int p = cnt + lane; p < pc; p += 64) row_tok[off + p] = -1;
}

// ------- mlp1: h = silu(x@G^T)*(x@U^T), BM=128, BN=64/mat, LDS 64KB ---------
// 2 blocks/CU; 3-deep pipeline (two named prefetch sets -> counted vmcnt(8)).
__global__ __launch_bounds__(512, 4) void mlp1_kernel(
    const float* __restrict__ x,
    const float* __restrict__ gp, const float* __restrict__ upw,
    u16* __restrict__ h,
    const int* __restrict__ meta, const int* __restrict__ te128,
    const int* __restrict__ tr128, const int* __restrict__ row_tok)
{
    const int tile = blockIdx.y;             // raw ids: dead tiles spread over XCDs
    const int nb = blockIdx.x;               // gridDim.x = FDIM/64 = 22
    if (tile >= meta[0]) return;
    const int n0 = nb * 64;
    const int e = te128[tile];
    const int r0g = tr128[tile];

    __shared__ __align__(16) u16 As[2][128 * 64];    // 16 KB / buf
    __shared__ __align__(16) u16 Bs0[2][64 * 64];    //  8 KB / buf
    __shared__ __align__(16) u16 Bs1[2][64 * 64];    //  8 KB / buf

    const int t = threadIdx.x;
    const int r16 = t >> 4, c4 = t & 15;     // rows r16(+32i), float4-col c4

    const float* arow[4]; bool avalid[4];
    #pragma unroll
    for (int i = 0; i < 4; i++) {
        const int tok = row_tok[r0g + r16 + 32 * i];
        avalid[i] = (tok >= 0);
        arow[i] = x + (size_t)(tok < 0 ? 0 : tok) * DDIM + c4 * 4;
    }
    const float* brow0[2];
    const float* brow1[2];
    {
        const float* B0 = gp + (size_t)e * FDIM * DDIM;
        const float* B1 = upw + (size_t)e * FDIM * DDIM;
        #pragma unroll
        for (int i = 0; i < 2; i++) {
            brow0[i] = B0 + (size_t)(n0 + r16 + 32 * i) * DDIM + c4 * 4;
            brow1[i] = B1 + (size_t)(n0 + r16 + 32 * i) * DDIM + c4 * 4;
        }
    }
    int sOffA[4], sOffB[2];
    #pragma unroll
    for (int i = 0; i < 4; i++) {
        const int row = r16 + 32 * i;
        sOffA[i] = row * 64 + (((c4 >> 1) ^ (row & 7)) * 8) + (c4 & 1) * 4;
    }
    #pragma unroll
    for (int i = 0; i < 2; i++) {
        const int row = r16 + 32 * i;
        sOffB[i] = row * 64 + (((c4 >> 1) ^ (row & 7)) * 8) + (c4 & 1) * 4;
    }

    const int wid = t >> 6, lane = t & 63;
    const int wm = (wid >> 1) * 32, wn = (wid & 1) * 32;   // wave tile 32x32
    const int lr = lane & 15, lhi = lane >> 4;

    f32x4 acc0[2][2], acc1[2][2];
    #pragma unroll
    for (int m = 0; m < 2; m++)
        #pragma unroll
        for (int n = 0; n < 2; n++) {
            acc0[m][n] = f32x4{0.f, 0.f, 0.f, 0.f};
            acc1[m][n] = f32x4{0.f, 0.f, 0.f, 0.f};
        }

    // two named prefetch sets (32 VGPR each) — static indexing only
    float4 paP[4], pb0P[2], pb1P[2];
    float4 paQ[4], pb0Q[2], pb1Q[2];

    auto LOAD_P = [&](int k0) {
        #pragma unroll
        for (int i = 0; i < 4; i++)
            paP[i] = avalid[i] ? *(const float4*)(arow[i] + k0)
                               : make_float4(0.f, 0.f, 0.f, 0.f);
        #pragma unroll
        for (int i = 0; i < 2; i++) pb0P[i] = *(const float4*)(brow0[i] + k0);
        #pragma unroll
        for (int i = 0; i < 2; i++) pb1P[i] = *(const float4*)(brow1[i] + k0);
    };
    auto LOAD_Q = [&](int k0) {
        #pragma unroll
        for (int i = 0; i < 4; i++)
            paQ[i] = avalid[i] ? *(const float4*)(arow[i] + k0)
                               : make_float4(0.f, 0.f, 0.f, 0.f);
        #pragma unroll
        for (int i = 0; i < 2; i++) pb0Q[i] = *(const float4*)(brow0[i] + k0);
        #pragma unroll
        for (int i = 0; i < 2; i++) pb1Q[i] = *(const float4*)(brow1[i] + k0);
    };
    auto STORE_P = [&](int bsel) {
        #pragma unroll
        for (int i = 0; i < 4; i++) {
            uint2 v; v.x = pack2(paP[i].x, paP[i].y); v.y = pack2(paP[i].z, paP[i].w);
            *(uint2*)(&As[bsel][sOffA[i]]) = v;
        }
        #pragma unroll
        for (int i = 0; i < 2; i++) {
            uint2 v; v.x = pack2(pb0P[i].x, pb0P[i].y); v.y = pack2(pb0P[i].z, pb0P[i].w);
            *(uint2*)(&Bs0[bsel][sOffB[i]]) = v;
        }
        #pragma unroll
        for (int i = 0; i < 2; i++) {
            uint2 v; v.x = pack2(pb1P[i].x, pb1P[i].y); v.y = pack2(pb1P[i].z, pb1P[i].w);
            *(uint2*)(&Bs1[bsel][sOffB[i]]) = v;
        }
    };
    auto STORE_Q = [&](int bsel) {
        #pragma unroll
        for (int i = 0; i < 4; i++) {
            uint2 v; v.x = pack2(paQ[i].x, paQ[i].y); v.y = pack2(paQ[i].z, paQ[i].w);
            *(uint2*)(&As[bsel][sOffA[i]]) = v;
        }
        #pragma unroll
        for (int i = 0; i < 2; i++) {
            uint2 v; v.x = pack2(pb0Q[i].x, pb0Q[i].y); v.y = pack2(pb0Q[i].z, pb0Q[i].w);
            *(uint2*)(&Bs0[bsel][sOffB[i]]) = v;
        }
        #pragma unroll
        for (int i = 0; i < 2; i++) {
            uint2 v; v.x = pack2(pb1Q[i].x, pb1Q[i].y); v.y = pack2(pb1Q[i].z, pb1Q[i].w);
            *(uint2*)(&Bs1[bsel][sOffB[i]]) = v;
        }
    };
    auto COMPUTE = [&](int bsel) {
        #pragma unroll
        for (int ks = 0; ks < 2; ks++) {
            short8 a[2], b0[2], b1[2];
            #pragma unroll
            for (int m = 0; m < 2; m++) {
                const int row = wm + m * 16 + lr;
                const int gr = (ks * 4 + lhi) ^ (row & 7);
                a[m] = *(const short8*)(&As[bsel][row * 64 + gr * 8]);
            }
            #pragma unroll
            for (int n = 0; n < 2; n++) {
                const int row = wn + n * 16 + lr;
                const int gr = (ks * 4 + lhi) ^ (row & 7);
                b0[n] = *(const short8*)(&Bs0[bsel][row * 64 + gr * 8]);
                b1[n] = *(const short8*)(&Bs1[bsel][row * 64 + gr * 8]);
            }
            #pragma unroll
            for (int m = 0; m < 2; m++)
                #pragma unroll
                for (int n = 0; n < 2; n++) {
                    acc0[m][n] = __builtin_amdgcn_mfma_f32_16x16x32_bf16(a[m], b0[n], acc0[m][n], 0, 0, 0);
                    acc1[m][n] = __builtin_amdgcn_mfma_f32_16x16x32_bf16(a[m], b1[n], acc1[m][n], 0, 0, 0);
                }
        }
    };

    constexpr int NT = DDIM / 64;            // 32 (even)
    // 3-deep prologue: P=k0, Q=k1 in flight; storing P waits only P (vmcnt(8))
    LOAD_P(0); LOAD_Q(64);
    STORE_P(0);
    __syncthreads();
    for (int kt = 0; kt < NT; kt += 2) {
        if (kt + 2 < NT) LOAD_P((kt + 2) * 64);
        COMPUTE(0);
        STORE_Q(1);                          // waits Q; P stays in flight
        __syncthreads();
        if (kt + 3 < NT) LOAD_Q((kt + 3) * 64);
        COMPUTE(1);
        if (kt + 2 < NT) {
            STORE_P(0);                      // waits P; Q stays in flight
            __syncthreads();
        }
    }

    // epilogue: h = silu(g)*u, bf16.  C/D: col=lane&15, row=(lane>>4)*4+reg
    #pragma unroll
    for (int m = 0; m < 2; m++) {
        const int rowb = r0g + wm + m * 16 + lhi * 4;
        #pragma unroll
        for (int n = 0; n < 2; n++) {
            const int col = n0 + wn + n * 16 + lr;
            #pragma unroll
            for (int j = 0; j < 4; j++) {
                const float g = acc0[m][n][j], u = acc1[m][n][j];
                const float hv = g / (1.f + __expf(-g)) * u;
                h[(size_t)(rowb + j) * FDIM + col] = f2bf(hv);
            }
        }
    }
}

// ---------------- down: eo = h @ D^T (bf16 out), BM=128, BN=128 -------------
// LDS 64KB -> 2 blocks/CU; 3-deep pipeline like mlp1.
__global__ __launch_bounds__(512, 4) void down_kernel(
    const u16* __restrict__ h, const float* __restrict__ dp,
    u16* __restrict__ eo,
    const int* __restrict__ meta, const int* __restrict__ te128,
    const int* __restrict__ tr128)
{
    const int tile = blockIdx.y;
    const int nb = blockIdx.x;               // gridDim.x = DDIM/128 = 16
    if (tile >= meta[0]) return;
    const int n0 = nb * 128;
    const int e = te128[tile];
    const int r0g = tr128[tile];

    __shared__ __align__(16) u16 As[2][128 * 64];
    __shared__ __align__(16) u16 Bs[2][128 * 64];

    const int t = threadIdx.x;
    const int r8 = t >> 3, g8 = t & 7;       // A: rows r8+64i, 16B granule g8
    const int r16 = t >> 4, c4 = t & 15;     // B: rows r16+32i, float4-col c4

    const u16* arow[2];
    int sOffA[2];
    #pragma unroll
    for (int i = 0; i < 2; i++) {
        const int row = r8 + 64 * i;
        arow[i] = h + (size_t)(r0g + row) * FDIM + g8 * 8;
        sOffA[i] = row * 64 + ((g8 ^ (row & 7)) * 8);
    }
    const float* brow[4];
    int sOffB[4];
    {
        const float* B = dp + (size_t)e * DDIM * FDIM;
        #pragma unroll
        for (int i = 0; i < 4; i++) {
            const int row = r16 + 32 * i;
            brow[i] = B + (size_t)(n0 + row) * FDIM + c4 * 4;
            sOffB[i] = row * 64 + (((c4 >> 1) ^ (row & 7)) * 8) + (c4 & 1) * 4;
        }
    }

    const int wid = t >> 6, lane = t & 63;
    const int wm = (wid >> 2) * 64, wn = (wid & 3) * 32;   // wave tile 64x32
    const int lr = lane & 15, lhi = lane >> 4;

    f32x4 acc[4][2];
    #pragma unroll
    for (int m = 0; m < 4; m++)
        #pragma unroll
        for (int n = 0; n < 2; n++)
            acc[m][n] = f32x4{0.f, 0.f, 0.f, 0.f};

    uint4 paP[2]; float4 pbP[4];
    uint4 paQ[2]; float4 pbQ[4];

    auto LOAD_P = [&](int k0) {
        #pragma unroll
        for (int i = 0; i < 2; i++) paP[i] = *(const uint4*)(arow[i] + k0);
        #pragma unroll
        for (int i = 0; i < 4; i++) pbP[i] = *(const float4*)(brow[i] + k0);
    };
    auto LOAD_Q = [&](int k0) {
        #pragma unroll
        for (int i = 0; i < 2; i++) paQ[i] = *(const uint4*)(arow[i] + k0);
        #pragma unroll
        for (int i = 0; i < 4; i++) pbQ[i] = *(const float4*)(brow[i] + k0);
    };
    auto STORE_P = [&](int bsel) {
        #pragma unroll
        for (int i = 0; i < 2; i++) *(uint4*)(&As[bsel][sOffA[i]]) = paP[i];
        #pragma unroll
        for (int i = 0; i < 4; i++) {
            uint2 v; v.x = pack2(pbP[i].x, pbP[i].y); v.y = pack2(pbP[i].z, pbP[i].w);
            *(uint2*)(&Bs[bsel][sOffB[i]]) = v;
        }
    };
    auto STORE_Q = [&](int bsel) {
        #pragma unroll
        for (int i = 0; i < 2; i++) *(uint4*)(&As[bsel][sOffA[i]]) = paQ[i];
        #pragma unroll
        for (int i = 0; i < 4; i++) {
            uint2 v; v.x = pack2(pbQ[i].x, pbQ[i].y); v.y = pack2(pbQ[i].z, pbQ[i].w);
            *(uint2*)(&Bs[bsel][sOffB[i]]) = v;
        }
    };
    auto COMPUTE = [&](int bsel) {
        #pragma unroll
        for (int ks = 0; ks < 2; ks++) {
            short8 a[4], b[2];
            #pragma unroll
            for (int m = 0; m < 4; m++) {
                const int row = wm + m * 16 + lr;
                const int gr = (ks * 4 + lhi) ^ (row & 7);
                a[m] = *(const short8*)(&As[bsel][row * 64 + gr * 8]);
            }
            #pragma unroll
            for (int n = 0; n < 2; n++) {
                const int row = wn + n * 16 + lr;
                const int gr = (ks * 4 + lhi) ^ (row & 7);
                b[n] = *(const short8*)(&Bs[bsel][row * 64 + gr * 8]);
            }
            #pragma unroll
            for (int m = 0; m < 4; m++)
                #pragma unroll
                for (int n = 0; n < 2; n++)
                    acc[m][n] = __builtin_amdgcn_mfma_f32_16x16x32_bf16(a[m], b[n], acc[m][n], 0, 0, 0);
        }
    };

    constexpr int NT = FDIM / 64;            // 22 (even)
    LOAD_P(0); LOAD_Q(64);
    STORE_P(0);
    __syncthreads();
    for (int kt = 0; kt < NT; kt += 2) {
        if (kt + 2 < NT) LOAD_P((kt + 2) * 64);
        COMPUTE(0);
        STORE_Q(1);
        __syncthreads();
        if (kt + 3 < NT) LOAD_Q((kt + 3) * 64);
        COMPUTE(1);
        if (kt + 2 < NT) {
            STORE_P(0);
            __syncthreads();
        }
    }

    #pragma unroll
    for (int m = 0; m < 4; m++) {
        const int rowb = r0g + wm + m * 16 + lhi * 4;
        #pragma unroll
        for (int n = 0; n < 2; n++) {
            const int col = n0 + wn + n * 16 + lr;
            #pragma unroll
            for (int j = 0; j < 4; j++)
                eo[(size_t)(rowb + j) * DDIM + col] = f2bf(acc[m][n][j]);
        }
    }
}

// ---------------- combine: out[t] = w1*eo[r1] + w2*eo[r2] (eo bf16) ---------
__global__ __launch_bounds__(256) void combine_kernel(
    const u16* __restrict__ eo, const int* __restrict__ tok_rows,
    const float* __restrict__ w, float* __restrict__ out)
{
    const int tok = blockIdx.x;
    const int r1 = tok_rows[tok * 2], r2 = tok_rows[tok * 2 + 1];
    const float w1 = w[tok * 2], w2 = w[tok * 2 + 1];
    const int d = threadIdx.x * 8;
    const uint4 a = *(const uint4*)(eo + (size_t)r1 * DDIM + d);
    const uint4 b = *(const uint4*)(eo + (size_t)r2 * DDIM + d);
    const u32 av[4] = {a.x, a.y, a.z, a.w};
    const u32 bv[4] = {b.x, b.y, b.z, b.w};
    float4 o0, o1;
    float* op[8] = {&o0.x, &o0.y, &o0.z, &o0.w, &o1.x, &o1.y, &o1.z, &o1.w};
    #pragma unroll
    for (int i = 0; i < 4; i++) {
        *op[2 * i]     = w1 * bf2f((u16)(av[i] & 0xffff)) + w2 * bf2f((u16)(bv[i] & 0xffff));
        *op[2 * i + 1] = w1 * bf2f((u16)(av[i] >> 16))    + w2 * bf2f((u16)(bv[i] >> 16));
    }
    float4* po = (float4*)(out + (size_t)tok * DDIM + d);
    po[0] = o0; po[1] = o1;
}

extern "C" void kernel_launch(void* const* d_in, const int* in_sizes, int n_in,
                              void* d_out, int out_size, void* d_ws, size_t ws_size,
                              hipStream_t stream) {
    const float* x  = (const float*)d_in[0];
    const float* gw = (const float*)d_in[1];
    const float* gp = (const float*)d_in[2];
    const float* up = (const float*)d_in[3];
    const float* dp = (const float*)d_in[4];
    float* out = (float*)d_out;
    char* ws = (char*)d_ws;

    int*   meta     = (int*)(ws + O_META);
    int*   te128    = (int*)(ws + O_TE128);
    int*   tr128    = (int*)(ws + O_TR128);
    int*   row_tok  = (int*)(ws + O_ROWTOK);
    int*   tok_rows = (int*)(ws + O_TOKROWS);
    int*   sel      = (int*)(ws + O_SEL);
    float* w        = (float*)(ws + O_W);
    u16*   h        = (u16*)(ws + O_H);
    u16*   eo       = (u16*)(ws + O_EO);

    router_kernel<<<N_TOK, 256, 0, stream>>>(x, gw, sel, w);
    build_kernel<<<1, 512, 0, stream>>>(sel, meta, te128, tr128, row_tok, tok_rows);
    mlp1_kernel<<<dim3(FDIM / 64, NT128), 512, 0, stream>>>(
        x, gp, up, h, meta, te128, tr128, row_tok);
    down_kernel<<<dim3(DDIM / 128, NT128), 512, 0, stream>>>(
        h, dp, eo, meta, te128, tr128);
    combine_kernel<<<N_TOK, 256, 0, stream>>>(eo, tok_rows, w, out);
}

// Round 7
// 196.802 us; speedup vs baseline: 3.1299x; 3.1299x over previous
//
#include <hip/hip_runtime.h>
#include <hip/hip_bf16.h>
#include <stdint.h>

typedef __attribute__((ext_vector_type(8))) short short8;
typedef __attribute__((ext_vector_type(4))) float f32x4;
typedef unsigned int u32;
typedef unsigned short u16;

static constexpr int N_TOK = 1024;
static constexpr int DDIM = 2048;
static constexpr int FDIM = 1408;
static constexpr int NEXP = 8;
static constexpr int MAXROWS = 3072;    // 2048 + 8*127 < 3072 (128-row padding)
static constexpr int NT128 = 24;        // max 128-row tiles

// ---- workspace byte offsets ----
static constexpr size_t O_META   = 0;                                  // 64 ints
static constexpr size_t O_TE128  = 256;                                // 24 ints
static constexpr size_t O_TR128  = 384;                                // 24 ints
static constexpr size_t O_ROWTOK = 768;                                // MAXROWS ints
static constexpr size_t O_TOKROWS= O_ROWTOK + (size_t)MAXROWS * 4;     // 2048 ints
static constexpr size_t O_SEL    = O_TOKROWS + 2048 * 4;               // 2048 ints
static constexpr size_t O_W      = O_SEL + 2048 * 4;                   // 2048 floats
static constexpr size_t O_H      = (O_W + 2048 * 4 + 255) & ~(size_t)255; // MAXROWS*FDIM bf16
static constexpr size_t O_EO     = O_H + (size_t)MAXROWS * FDIM * 2;   // MAXROWS*DDIM bf16

static __device__ __forceinline__ u16 f2bf(float f) {
    return __builtin_bit_cast(u16, __float2bfloat16(f));   // RNE via v_cvt
}
static __device__ __forceinline__ float bf2f(u16 s) {
    u32 u = ((u32)s) << 16;
    return __builtin_bit_cast(float, u);
}
static __device__ __forceinline__ u32 pack2(float a, float b) {
    return (u32)f2bf(a) | ((u32)f2bf(b) << 16);
}

// ---------------- router: logits, top-2, softmax ----------------
__global__ __launch_bounds__(256) void router_kernel(
    const float* __restrict__ x, const float* __restrict__ gw,
    int* __restrict__ sel, float* __restrict__ wout)
{
    __shared__ float xs[DDIM];
    __shared__ float lg[NEXP];
    const int tok = blockIdx.x;
    const float* xr = x + (size_t)tok * DDIM;
    for (int i = threadIdx.x; i < DDIM / 4; i += 256)
        ((float4*)xs)[i] = ((const float4*)xr)[i];
    __syncthreads();
    const int wid = threadIdx.x >> 6, lane = threadIdx.x & 63;
    for (int i = 0; i < 2; i++) {
        const int e = wid * 2 + i;
        const float* g = gw + (size_t)e * DDIM;
        float s = 0.f;
        for (int k = lane; k < DDIM; k += 64) s += xs[k] * g[k];
        for (int off = 32; off > 0; off >>= 1) s += __shfl_down(s, off);
        if (lane == 0) lg[e] = s;
    }
    __syncthreads();
    if (threadIdx.x == 0) {
        int i1 = 0;
        for (int e = 1; e < NEXP; e++) if (lg[e] > lg[i1]) i1 = e;
        int i2 = -1;
        for (int e = 0; e < NEXP; e++) {
            if (e == i1) continue;
            if (i2 < 0 || lg[e] > lg[i2]) i2 = e;
        }
        const float e2 = __expf(lg[i2] - lg[i1]);
        const float w1 = 1.f / (1.f + e2);
        sel[tok * 2] = i1; sel[tok * 2 + 1] = i2;
        wout[tok * 2] = w1; wout[tok * 2 + 1] = e2 * w1;
    }
}

// -------- deterministic routing build (1 block, 8 waves); 128-row padding ----
__global__ __launch_bounds__(512) void build_kernel(
    const int* __restrict__ sel,
    int* __restrict__ meta, int* __restrict__ te128, int* __restrict__ tr128,
    int* __restrict__ row_tok, int* __restrict__ tok_rows)
{
    __shared__ int s0[N_TOK], s1[N_TOK];
    __shared__ u16 p0[N_TOK], p1[N_TOK];
    __shared__ int counts[NEXP], offs[NEXP];
    for (int i = threadIdx.x; i < N_TOK; i += 512) {
        s0[i] = sel[i * 2]; s1[i] = sel[i * 2 + 1];
    }
    __syncthreads();
    const int e = threadIdx.x >> 6, lane = threadIdx.x & 63;
    int base = 0;
    for (int c = 0; c < N_TOK / 64; c++) {
        const int tk = c * 64 + lane;
        const int slot = (s0[tk] == e) ? 0 : ((s1[tk] == e) ? 1 : -1);
        const unsigned long long m = __ballot(slot >= 0);
        const int pre = __popcll(m & ((1ull << lane) - 1ull));
        if (slot == 0) p0[tk] = (u16)(base + pre);
        else if (slot == 1) p1[tk] = (u16)(base + pre);
        base += __popcll(m);
    }
    if (lane == 0) counts[e] = base;
    __syncthreads();
    if (threadIdx.x == 0) {
        int off = 0, n128 = 0;
        for (int qq = 0; qq < NEXP; qq++) {
            offs[qq] = off;
            const int pc = (counts[qq] + 127) & ~127;
            for (int i = 0; i < pc / 128; i++) { te128[n128] = qq; tr128[n128] = off + i * 128; n128++; }
            off += pc;
        }
        meta[0] = n128; meta[1] = off;
    }
    __syncthreads();
    const int off = offs[e];
    for (int c = 0; c < N_TOK / 64; c++) {
        const int tk = c * 64 + lane;
        const int slot = (s0[tk] == e) ? 0 : ((s1[tk] == e) ? 1 : -1);
        if (slot >= 0) {
            const int row = off + (slot ? p1[tk] : p0[tk]);
            row_tok[row] = tk;
            tok_rows[tk * 2 + slot] = row;
        }
    }
    const int cnt = counts[e];
    const int pc = (cnt + 127) & ~127;
    for (int p = cnt + lane; p < pc; p += 64) row_tok[off + p] = -1;
}

// ------- mlp1: h = silu(x@G^T)*(x@U^T), BM=128, BN=64/mat, LDS 64KB ---------
// 2 blocks/CU; 2-deep pipeline, SINGLE prefetch set (VGPR ~60, no spill).
// Raw blockIdx (no XCD remap): dead tiles spread round-robin over XCDs.
__global__ __launch_bounds__(512, 4) void mlp1_kernel(
    const float* __restrict__ x,
    const float* __restrict__ gp, const float* __restrict__ upw,
    u16* __restrict__ h,
    const int* __restrict__ meta, const int* __restrict__ te128,
    const int* __restrict__ tr128, const int* __restrict__ row_tok)
{
    const int tile = blockIdx.y;
    const int nb = blockIdx.x;               // gridDim.x = FDIM/64 = 22
    if (tile >= meta[0]) return;
    const int n0 = nb * 64;
    const int e = te128[tile];
    const int r0g = tr128[tile];

    __shared__ __align__(16) u16 As[2][128 * 64];    // 16 KB / buf
    __shared__ __align__(16) u16 Bs0[2][64 * 64];    //  8 KB / buf
    __shared__ __align__(16) u16 Bs1[2][64 * 64];    //  8 KB / buf

    const int t = threadIdx.x;
    const int r16 = t >> 4, c4 = t & 15;     // rows r16(+32i), float4-col c4

    const float* arow[4]; bool avalid[4];
    #pragma unroll
    for (int i = 0; i < 4; i++) {
        const int tok = row_tok[r0g + r16 + 32 * i];
        avalid[i] = (tok >= 0);
        arow[i] = x + (size_t)(tok < 0 ? 0 : tok) * DDIM + c4 * 4;
    }
    const float* brow0[2];
    const float* brow1[2];
    {
        const float* B0 = gp + (size_t)e * FDIM * DDIM;
        const float* B1 = upw + (size_t)e * FDIM * DDIM;
        #pragma unroll
        for (int i = 0; i < 2; i++) {
            brow0[i] = B0 + (size_t)(n0 + r16 + 32 * i) * DDIM + c4 * 4;
            brow1[i] = B1 + (size_t)(n0 + r16 + 32 * i) * DDIM + c4 * 4;
        }
    }
    int sOffA[4], sOffB[2];
    #pragma unroll
    for (int i = 0; i < 4; i++) {
        const int row = r16 + 32 * i;
        sOffA[i] = row * 64 + (((c4 >> 1) ^ (row & 7)) * 8) + (c4 & 1) * 4;
    }
    #pragma unroll
    for (int i = 0; i < 2; i++) {
        const int row = r16 + 32 * i;
        sOffB[i] = row * 64 + (((c4 >> 1) ^ (row & 7)) * 8) + (c4 & 1) * 4;
    }

    const int wid = t >> 6, lane = t & 63;
    const int wm = (wid >> 1) * 32, wn = (wid & 1) * 32;   // wave tile 32x32
    const int lr = lane & 15, lhi = lane >> 4;

    f32x4 acc0[2][2], acc1[2][2];
    #pragma unroll
    for (int m = 0; m < 2; m++)
        #pragma unroll
        for (int n = 0; n < 2; n++) {
            acc0[m][n] = f32x4{0.f, 0.f, 0.f, 0.f};
            acc1[m][n] = f32x4{0.f, 0.f, 0.f, 0.f};
        }

    float4 pa[4], pb0[2], pb1[2];            // single prefetch set (32 VGPR)

    auto LOAD = [&](int k0) {
        #pragma unroll
        for (int i = 0; i < 4; i++)
            pa[i] = avalid[i] ? *(const float4*)(arow[i] + k0)
                              : make_float4(0.f, 0.f, 0.f, 0.f);
        #pragma unroll
        for (int i = 0; i < 2; i++) pb0[i] = *(const float4*)(brow0[i] + k0);
        #pragma unroll
        for (int i = 0; i < 2; i++) pb1[i] = *(const float4*)(brow1[i] + k0);
    };
    auto STORE = [&](int bsel) {
        #pragma unroll
        for (int i = 0; i < 4; i++) {
            uint2 v; v.x = pack2(pa[i].x, pa[i].y); v.y = pack2(pa[i].z, pa[i].w);
            *(uint2*)(&As[bsel][sOffA[i]]) = v;
        }
        #pragma unroll
        for (int i = 0; i < 2; i++) {
            uint2 v; v.x = pack2(pb0[i].x, pb0[i].y); v.y = pack2(pb0[i].z, pb0[i].w);
            *(uint2*)(&Bs0[bsel][sOffB[i]]) = v;
        }
        #pragma unroll
        for (int i = 0; i < 2; i++) {
            uint2 v; v.x = pack2(pb1[i].x, pb1[i].y); v.y = pack2(pb1[i].z, pb1[i].w);
            *(uint2*)(&Bs1[bsel][sOffB[i]]) = v;
        }
    };
    auto COMPUTE = [&](int bsel) {
        #pragma unroll
        for (int ks = 0; ks < 2; ks++) {
            short8 a[2], b0[2], b1[2];
            #pragma unroll
            for (int m = 0; m < 2; m++) {
                const int row = wm + m * 16 + lr;
                const int gr = (ks * 4 + lhi) ^ (row & 7);
                a[m] = *(const short8*)(&As[bsel][row * 64 + gr * 8]);
            }
            #pragma unroll
            for (int n = 0; n < 2; n++) {
                const int row = wn + n * 16 + lr;
                const int gr = (ks * 4 + lhi) ^ (row & 7);
                b0[n] = *(const short8*)(&Bs0[bsel][row * 64 + gr * 8]);
                b1[n] = *(const short8*)(&Bs1[bsel][row * 64 + gr * 8]);
            }
            #pragma unroll
            for (int m = 0; m < 2; m++)
                #pragma unroll
                for (int n = 0; n < 2; n++) {
                    acc0[m][n] = __builtin_amdgcn_mfma_f32_16x16x32_bf16(a[m], b0[n], acc0[m][n], 0, 0, 0);
                    acc1[m][n] = __builtin_amdgcn_mfma_f32_16x16x32_bf16(a[m], b1[n], acc1[m][n], 0, 0, 0);
                }
        }
    };

    constexpr int NT = DDIM / 64;            // 32
    LOAD(0); STORE(0);
    __syncthreads();
    for (int kt = 0; kt < NT; kt++) {
        const int cur = kt & 1;
        if (kt + 1 < NT) LOAD((kt + 1) * 64);
        COMPUTE(cur);
        if (kt + 1 < NT) {
            STORE(cur ^ 1);
            __syncthreads();
        }
    }

    // epilogue: h = silu(g)*u, bf16.  C/D: col=lane&15, row=(lane>>4)*4+reg
    #pragma unroll
    for (int m = 0; m < 2; m++) {
        const int rowb = r0g + wm + m * 16 + lhi * 4;
        #pragma unroll
        for (int n = 0; n < 2; n++) {
            const int col = n0 + wn + n * 16 + lr;
            #pragma unroll
            for (int j = 0; j < 4; j++) {
                const float g = acc0[m][n][j], u = acc1[m][n][j];
                const float hv = g / (1.f + __expf(-g)) * u;
                h[(size_t)(rowb + j) * FDIM + col] = f2bf(hv);
            }
        }
    }
}

// ---------------- down: eo = h @ D^T (bf16 out), BM=128, BN=128 -------------
// LDS 64KB -> 2 blocks/CU; 2-deep, single prefetch set; raw blockIdx.
__global__ __launch_bounds__(512, 4) void down_kernel(
    const u16* __restrict__ h, const float* __restrict__ dp,
    u16* __restrict__ eo,
    const int* __restrict__ meta, const int* __restrict__ te128,
    const int* __restrict__ tr128)
{
    const int tile = blockIdx.y;
    const int nb = blockIdx.x;               // gridDim.x = DDIM/128 = 16
    if (tile >= meta[0]) return;
    const int n0 = nb * 128;
    const int e = te128[tile];
    const int r0g = tr128[tile];

    __shared__ __align__(16) u16 As[2][128 * 64];
    __shared__ __align__(16) u16 Bs[2][128 * 64];

    const int t = threadIdx.x;
    const int r8 = t >> 3, g8 = t & 7;       // A: rows r8+64i, 16B granule g8
    const int r16 = t >> 4, c4 = t & 15;     // B: rows r16+32i, float4-col c4

    const u16* arow[2];
    int sOffA[2];
    #pragma unroll
    for (int i = 0; i < 2; i++) {
        const int row = r8 + 64 * i;
        arow[i] = h + (size_t)(r0g + row) * FDIM + g8 * 8;
        sOffA[i] = row * 64 + ((g8 ^ (row & 7)) * 8);
    }
    const float* brow[4];
    int sOffB[4];
    {
        const float* B = dp + (size_t)e * DDIM * FDIM;
        #pragma unroll
        for (int i = 0; i < 4; i++) {
            const int row = r16 + 32 * i;
            brow[i] = B + (size_t)(n0 + row) * FDIM + c4 * 4;
            sOffB[i] = row * 64 + (((c4 >> 1) ^ (row & 7)) * 8) + (c4 & 1) * 4;
        }
    }

    const int wid = t >> 6, lane = t & 63;
    const int wm = (wid >> 2) * 64, wn = (wid & 3) * 32;   // wave tile 64x32
    const int lr = lane & 15, lhi = lane >> 4;

    f32x4 acc[4][2];
    #pragma unroll
    for (int m = 0; m < 4; m++)
        #pragma unroll
        for (int n = 0; n < 2; n++)
            acc[m][n] = f32x4{0.f, 0.f, 0.f, 0.f};

    uint4 pa[2]; float4 pb[4];

    auto LOAD = [&](int k0) {
        #pragma unroll
        for (int i = 0; i < 2; i++) pa[i] = *(const uint4*)(arow[i] + k0);
        #pragma unroll
        for (int i = 0; i < 4; i++) pb[i] = *(const float4*)(brow[i] + k0);
    };
    auto STORE = [&](int bsel) {
        #pragma unroll
        for (int i = 0; i < 2; i++) *(uint4*)(&As[bsel][sOffA[i]]) = pa[i];
        #pragma unroll
        for (int i = 0; i < 4; i++) {
            uint2 v; v.x = pack2(pb[i].x, pb[i].y); v.y = pack2(pb[i].z, pb[i].w);
            *(uint2*)(&Bs[bsel][sOffB[i]]) = v;
        }
    };
    auto COMPUTE = [&](int bsel) {
        #pragma unroll
        for (int ks = 0; ks < 2; ks++) {
            short8 a[4], b[2];
            #pragma unroll
            for (int m = 0; m < 4; m++) {
                const int row = wm + m * 16 + lr;
                const int gr = (ks * 4 + lhi) ^ (row & 7);
                a[m] = *(const short8*)(&As[bsel][row * 64 + gr * 8]);
            }
            #pragma unroll
            for (int n = 0; n < 2; n++) {
                const int row = wn + n * 16 + lr;
                const int gr = (ks * 4 + lhi) ^ (row & 7);
                b[n] = *(const short8*)(&Bs[bsel][row * 64 + gr * 8]);
            }
            #pragma unroll
            for (int m = 0; m < 4; m++)
                #pragma unroll
                for (int n = 0; n < 2; n++)
                    acc[m][n] = __builtin_amdgcn_mfma_f32_16x16x32_bf16(a[m], b[n], acc[m][n], 0, 0, 0);
        }
    };

    constexpr int NT = FDIM / 64;            // 22
    LOAD(0); STORE(0);
    __syncthreads();
    for (int kt = 0; kt < NT; kt++) {
        const int cur = kt & 1;
        if (kt + 1 < NT) LOAD((kt + 1) * 64);
        COMPUTE(cur);
        if (kt + 1 < NT) {
            STORE(cur ^ 1);
            __syncthreads();
        }
    }

    #pragma unroll
    for (int m = 0; m < 4; m++) {
        const int rowb = r0g + wm + m * 16 + lhi * 4;
        #pragma unroll
        for (int n = 0; n < 2; n++) {
            const int col = n0 + wn + n * 16 + lr;
            #pragma unroll
            for (int j = 0; j < 4; j++)
                eo[(size_t)(rowb + j) * DDIM + col] = f2bf(acc[m][n][j]);
        }
    }
}

// ---------------- combine: out[t] = w1*eo[r1] + w2*eo[r2] (eo bf16) ---------
__global__ __launch_bounds__(256) void combine_kernel(
    const u16* __restrict__ eo, const int* __restrict__ tok_rows,
    const float* __restrict__ w, float* __restrict__ out)
{
    const int tok = blockIdx.x;
    const int r1 = tok_rows[tok * 2], r2 = tok_rows[tok * 2 + 1];
    const float w1 = w[tok * 2], w2 = w[tok * 2 + 1];
    const int d = threadIdx.x * 8;
    const uint4 a = *(const uint4*)(eo + (size_t)r1 * DDIM + d);
    const uint4 b = *(const uint4*)(eo + (size_t)r2 * DDIM + d);
    const u32 av[4] = {a.x, a.y, a.z, a.w};
    const u32 bv[4] = {b.x, b.y, b.z, b.w};
    float4 o0, o1;
    float* op[8] = {&o0.x, &o0.y, &o0.z, &o0.w, &o1.x, &o1.y, &o1.z, &o1.w};
    #pragma unroll
    for (int i = 0; i < 4; i++) {
        *op[2 * i]     = w1 * bf2f((u16)(av[i] & 0xffff)) + w2 * bf2f((u16)(bv[i] & 0xffff));
        *op[2 * i + 1] = w1 * bf2f((u16)(av[i] >> 16))    + w2 * bf2f((u16)(bv[i] >> 16));
    }
    float4* po = (float4*)(out + (size_t)tok * DDIM + d);
    po[0] = o0; po[1] = o1;
}

extern "C" void kernel_launch(void* const* d_in, const int* in_sizes, int n_in,
                              void* d_out, int out_size, void* d_ws, size_t ws_size,
                              hipStream_t stream) {
    const float* x  = (const float*)d_in[0];
    const float* gw = (const float*)d_in[1];
    const float* gp = (const float*)d_in[2];
    const float* up = (const float*)d_in[3];
    const float* dp = (const float*)d_in[4];
    float* out = (float*)d_out;
    char* ws = (char*)d_ws;

    int*   meta     = (int*)(ws + O_META);
    int*   te128    = (int*)(ws + O_TE128);
    int*   tr128    = (int*)(ws + O_TR128);
    int*   row_tok  = (int*)(ws + O_ROWTOK);
    int*   tok_rows = (int*)(ws + O_TOKROWS);
    int*   sel      = (int*)(ws + O_SEL);
    float* w        = (float*)(ws + O_W);
    u16*   h        = (u16*)(ws + O_H);
    u16*   eo       = (u16*)(ws + O_EO);

    router_kernel<<<N_TOK, 256, 0, stream>>>(x, gw, sel, w);
    build_kernel<<<1, 512, 0, stream>>>(sel, meta, te128, tr128, row_tok, tok_rows);
    mlp1_kernel<<<dim3(FDIM / 64, NT128), 512, 0, stream>>>(
        x, gp, up, h, meta, te128, tr128, row_tok);
    down_kernel<<<dim3(DDIM / 128, NT128), 512, 0, stream>>>(
        h, dp, eo, meta, te128, tr128);
    combine_kernel<<<N_TOK, 256, 0, stream>>>(eo, tok_rows, w, out);
}